// Round 13
// baseline (237.259 us; speedup 1.0000x reference)
//
#include <hip/hip_runtime.h>

#define B_ 4
#define C_ 256
#define D_ 128
#define N_ 4096
#define LOG2E 1.44269504088896340736f
#define M_FIX 90.0f

typedef __attribute__((ext_vector_type(8))) short short8_t;
typedef __attribute__((ext_vector_type(4))) short short4_t;
typedef __attribute__((ext_vector_type(4))) float f32x4;
typedef _Float16 half8_t __attribute__((ext_vector_type(8)));
typedef _Float16 half4_t __attribute__((ext_vector_type(4)));

__device__ __forceinline__ unsigned short f2bf(float f) {
    union { float f; unsigned int u; } c; c.f = f;
    unsigned int r = (c.u + 0x7fffu + ((c.u >> 16) & 1u)) >> 16;
    return (unsigned short)r;
}
__device__ __forceinline__ float bf2f(unsigned int u) {
    union { unsigned int u; float f; } c; c.u = (u & 0xffffu) << 16;
    return c.f;
}
__device__ __forceinline__ unsigned short f2h(float f) {
    union { _Float16 h; unsigned short u; } c; c.h = (_Float16)f;
    return c.u;
}
__device__ __forceinline__ unsigned int cvtpk_bf16(float lo, float hi) {
    unsigned int r;
    asm("v_cvt_pk_bf16_f32 %0, %1, %2" : "=v"(r) : "v"(lo), "v"(hi));
    return r;
}

// direct HBM -> LDS DMA, 16 B per lane; lane i lands at lp + 16*i (linear)
#define GLOAD16(gp, lp)                                                     \
    __builtin_amdgcn_global_load_lds(                                       \
        (const __attribute__((address_space(1))) unsigned int*)(gp),        \
        (__attribute__((address_space(3))) unsigned int*)(lp), 16, 0, 0)

// ---------------------------------------------------------------------------
// Kernel 0: weight convert.
//   wF  [384][256] fp16 : rows 0-127 = LOG2E*w_theta, 128-255 = w_phi, 256-383 = w_g
//   woutF [256][128] bf16 : w_out
// ---------------------------------------------------------------------------
__global__ __launch_bounds__(256) void wcvt_kernel(
    const float* __restrict__ w_theta, const float* __restrict__ w_phi,
    const float* __restrict__ w_g, const float* __restrict__ w_out,
    unsigned short* __restrict__ wF, unsigned short* __restrict__ woutF)
{
    int tid = blockIdx.x * 256 + threadIdx.x;   // 131072 total
    if (tid < 3 * 32768) {
        int wi = tid >> 15, off = tid & 32767;
        const float* src = (wi == 0) ? w_theta : (wi == 1) ? w_phi : w_g;
        float v = src[off] * ((wi == 0) ? LOG2E : 1.f);
        wF[tid] = f2h(v);
    } else {
        int off = tid - 3 * 32768;
        woutF[off] = f2bf(w_out[off]);
    }
}

// ---------------------------------------------------------------------------
// Kernel 1: projections via MFMA.
// grid (N/32, B), 256 threads (4 waves). Block: n-tile 32, all 384 dd, k=256.
// x tile staged in LDS fp16 [256 c][32 n] (stride 36). x-fragments reused as
// A (for V, D[n][dd]) and B (for Q/K, D[dd][n]) operands. w frags from L2.
//   Q[b][n][dd] fp16 (log2e pre-scaled), K[b][n][dd] fp16, Vt[b][dd][n] bf16
// ---------------------------------------------------------------------------
__global__ __launch_bounds__(256) void proj_mfma(
    const float* __restrict__ x, const unsigned short* __restrict__ wF,
    unsigned short* __restrict__ Qf, unsigned short* __restrict__ Kf,
    unsigned short* __restrict__ Vt)
{
    const int n0 = blockIdx.x * 32;
    const int b  = blockIdx.y;

    __shared__ _Float16 xs[256 * 36];   // [c][n], stride 36 (2-way-free reads)

    const int t  = threadIdx.x;
    const int w  = t >> 6;
    const int l  = t & 63;
    const int lr = l & 15;
    const int lg = l >> 4;

    // stage x tile: pass p, thread: c = 32p + (t>>3), n = 4*(t&7)
    const float* xb = x + (size_t)b * C_ * N_;
    {
        const int cb = t >> 3, n2 = t & 7;
        #pragma unroll
        for (int p = 0; p < 8; ++p) {
            const int c = 32 * p + cb;
            float4 v = *reinterpret_cast<const float4*>(&xb[(size_t)c * N_ + n0 + 4 * n2]);
            union { _Float16 h[4]; uint2 u; } pk;
            pk.h[0] = (_Float16)v.x; pk.h[1] = (_Float16)v.y;
            pk.h[2] = (_Float16)v.z; pk.h[3] = (_Float16)v.w;
            *reinterpret_cast<uint2*>(&xs[c * 36 + 4 * n2]) = pk.u;
        }
    }
    __syncthreads();

    // wave w owns dd-tiles gt = 6w .. 6w+5 (each 16 dd rows of the 384)
    f32x4 acc[6][2];
    #pragma unroll
    for (int d = 0; d < 6; ++d)
        #pragma unroll
        for (int nt = 0; nt < 2; ++nt) acc[d][nt] = (f32x4){0.f, 0.f, 0.f, 0.f};

    #pragma unroll
    for (int kt = 0; kt < 8; ++kt) {
        // x fragments: lane (lr,lg) holds x[c = 32kt+8lg+j][n = 16nt+lr]
        half8_t xf[2];
        #pragma unroll
        for (int nt = 0; nt < 2; ++nt)
            #pragma unroll
            for (int j = 0; j < 8; ++j)
                xf[nt][j] = xs[(32 * kt + 8 * lg + j) * 36 + 16 * nt + lr];
        #pragma unroll
        for (int d = 0; d < 6; ++d) {
            const int gt = 6 * w + d;
            half8_t wf = *reinterpret_cast<const half8_t*>(
                &wF[(size_t)(16 * gt + lr) * 256 + 32 * kt + 8 * lg]);
            if (gt < 16) {   // Q/K: D[dd][n]
                #pragma unroll
                for (int nt = 0; nt < 2; ++nt)
                    acc[d][nt] = __builtin_amdgcn_mfma_f32_16x16x32_f16(wf, xf[nt], acc[d][nt], 0, 0, 0);
            } else {         // V: D[n][dd]
                #pragma unroll
                for (int nt = 0; nt < 2; ++nt)
                    acc[d][nt] = __builtin_amdgcn_mfma_f32_16x16x32_f16(xf[nt], wf, acc[d][nt], 0, 0, 0);
            }
        }
    }

    // stores
    #pragma unroll
    for (int d = 0; d < 6; ++d) {
        const int gt = 6 * w + d;
        #pragma unroll
        for (int nt = 0; nt < 2; ++nt) {
            if (gt < 16) {
                // D[dd][n]: col n = 16nt+lr, rows dd = (gt&7)*16 + 4lg + r
                unsigned short* o = (gt < 8) ? Qf : Kf;
                half4_t s;
                #pragma unroll
                for (int r = 0; r < 4; ++r) s[r] = (_Float16)acc[d][nt][r];
                size_t idx = ((size_t)(b * N_ + n0 + 16 * nt + lr)) * D_ + (gt & 7) * 16 + 4 * lg;
                *reinterpret_cast<half4_t*>(&o[idx]) = s;
            } else {
                // D[n][dd]: col dd = (gt-16)*16 + lr, rows n = 16nt + 4lg + r
                short4_t s;
                #pragma unroll
                for (int r = 0; r < 4; ++r) s[r] = (short)f2bf(acc[d][nt][r]);
                size_t idx = ((size_t)b * D_ + (gt - 16) * 16 + lr) * N_ + n0 + 16 * nt + 4 * lg;
                *reinterpret_cast<short4_t*>(&Vt[idx]) = s;
            }
        }
    }
}

// ---------------------------------------------------------------------------
// Kernel 2: MFMA flash attention.
// vs r12: V no longer staged in LDS — PV fragments are contiguous in
// Vt[b][dd][n], so they load straight from L2 into registers (bit-identical
// values). Halves the LDS-pipe load (the measured roofline) and LDS footprint.
// K stays gload_lds + swizzle, double-buffered. l via ones-row MFMA.
// ---------------------------------------------------------------------------
__global__ __launch_bounds__(512, 4) void flash_mfma(
    const unsigned short* __restrict__ Qg,   // fp16 [b][n][dd], log2e-scaled
    const unsigned short* __restrict__ Kg,   // fp16 [b][n][dd]
    const unsigned short* __restrict__ Vg,   // bf16 [b][dd][n]
    unsigned short* __restrict__ Yp, float* __restrict__ Lg)
{
    const int id    = blockIdx.x;
    const int local = id >> 3;
    const int group = (id & 7) * 2 + (local >> 5);
    const int qblk  = local & 31;
    const int h     = group & 3;
    const int b     = group >> 2;
    const int q0    = qblk * 128;
    const int m_base = h * 1024;

    __shared__ unsigned short Ks[2][64 * 128];   // fp16, swizzled c16 = j^(row&15)

    const int t  = threadIdx.x;
    const int w  = t >> 6;
    const int l  = t & 63;
    const int lr = l & 15;
    const int lg = l >> 4;

    half8_t qf[4];
    {
        const unsigned short* qp =
            Qg + ((size_t)(b * N_ + q0 + w * 16 + lr)) * D_ + lg * 8;
        #pragma unroll
        for (int kt = 0; kt < 4; ++kt)
            qf[kt] = *reinterpret_cast<const half8_t*>(qp + 32 * kt);
    }

    f32x4 Yf[8];
    #pragma unroll
    for (int i = 0; i < 8; ++i) Yf[i] = (f32x4){0.f, 0.f, 0.f, 0.f};
    f32x4 lacc = (f32x4){0.f, 0.f, 0.f, 0.f};   // l[q=lr] via ones-row MFMA

    short8_t ones;
    #pragma unroll
    for (int i = 0; i < 8; ++i) ones[i] = (short)0x3F80;   // bf16 1.0

    const unsigned short* Kbp = Kg + (size_t)b * N_ * D_;
    const int krow0 = 8 * w + (l >> 4);
    const int krow1 = krow0 + 4;
    const unsigned short* kp0 = Kbp + (size_t)(m_base + krow0) * D_ + (((l & 15) ^ (krow0 & 15)) * 8);
    const unsigned short* kp1 = Kbp + (size_t)(m_base + krow1) * D_ + (((l & 15) ^ (krow1 & 15)) * 8);

    // per-lane V base: V[dd = 16dt + lr][m = m_base + 64it + 32mk + 8lg ..+7]
    const unsigned short* vlane =
        Vg + (size_t)b * D_ * N_ + (size_t)lr * N_ + m_base + 8 * lg;

    GLOAD16(kp0, &Ks[0][(8 * w) * 128]);
    GLOAD16(kp1, &Ks[0][(8 * w + 4) * 128]);
    __syncthreads();

    for (int it = 0; it < 16; ++it) {
        const int cur = it & 1;
        if (it + 1 < 16) {
            const size_t ko = (size_t)(it + 1) * 8192;
            GLOAD16(kp0 + ko, &Ks[cur ^ 1][(8 * w) * 128]);
            GLOAD16(kp1 + ko, &Ks[cur ^ 1][(8 * w + 4) * 128]);
        }

        // S starts at -M_FIX (fixed-max shift folded into the accumulator)
        f32x4 S[4];
        #pragma unroll
        for (int mt = 0; mt < 4; ++mt)
            S[mt] = (f32x4){-M_FIX, -M_FIX, -M_FIX, -M_FIX};
        __builtin_amdgcn_s_setprio(1);
        #pragma unroll
        for (int kt = 0; kt < 4; ++kt) {
            #pragma unroll
            for (int mt = 0; mt < 4; ++mt) {
                const int row = lr + 16 * mt;
                const int off = row * 128 + (((lg + 4 * kt) ^ lr) * 8);
                half8_t kf = *reinterpret_cast<const half8_t*>(&Ks[cur][off]);
                S[mt] = __builtin_amdgcn_mfma_f32_16x16x32_f16(kf, qf[kt], S[mt], 0, 0, 0);
            }
        }
        __builtin_amdgcn_s_setprio(0);

        // issue V chunk mk=0 (L2-hot); latency hides under softmax VALU
        const unsigned short* vit = vlane + it * 64;
        short8_t vr0[8];
        #pragma unroll
        for (int dt = 0; dt < 8; ++dt)
            vr0[dt] = *reinterpret_cast<const short8_t*>(vit + (size_t)dt * 16 * N_);

        #pragma unroll
        for (int mt = 0; mt < 4; ++mt)
            #pragma unroll
            for (int r = 0; r < 4; ++r)
                S[mt][r] = exp2f(S[mt][r]);
        unsigned int pk[4][2];
        #pragma unroll
        for (int mt = 0; mt < 4; ++mt) {
            pk[mt][0] = cvtpk_bf16(S[mt][0], S[mt][1]);
            pk[mt][1] = cvtpk_bf16(S[mt][2], S[mt][3]);
        }

        // pb for mk=0
        short8_t pb0;
        {
            unsigned int* pbw = reinterpret_cast<unsigned int*>(&pb0);
            #pragma unroll
            for (int wd = 0; wd < 4; ++wd) {
                int src = lr + 16 * (2 * (lg & 1) + (wd >> 1));
                unsigned int vA = __shfl(pk[0][wd & 1], src, 64);
                unsigned int vB = __shfl(pk[1][wd & 1], src, 64);
                pbw[wd] = (lg >> 1) ? vB : vA;
            }
        }

        // issue V chunk mk=1; latency hides under mk=0's MFMAs
        short8_t vr1[8];
        #pragma unroll
        for (int dt = 0; dt < 8; ++dt)
            vr1[dt] = *reinterpret_cast<const short8_t*>(vit + (size_t)dt * 16 * N_ + 32);

        __builtin_amdgcn_s_setprio(1);
        #pragma unroll
        for (int dt = 0; dt < 8; ++dt)
            Yf[dt] = __builtin_amdgcn_mfma_f32_16x16x32_bf16(vr0[dt], pb0, Yf[dt], 0, 0, 0);
        lacc = __builtin_amdgcn_mfma_f32_16x16x32_bf16(ones, pb0, lacc, 0, 0, 0);
        __builtin_amdgcn_s_setprio(0);

        // pb for mk=1
        short8_t pb1;
        {
            unsigned int* pbw = reinterpret_cast<unsigned int*>(&pb1);
            #pragma unroll
            for (int wd = 0; wd < 4; ++wd) {
                int src = lr + 16 * (2 * (lg & 1) + (wd >> 1));
                unsigned int vA = __shfl(pk[2][wd & 1], src, 64);
                unsigned int vB = __shfl(pk[3][wd & 1], src, 64);
                pbw[wd] = (lg >> 1) ? vB : vA;
            }
        }

        __builtin_amdgcn_s_setprio(1);
        #pragma unroll
        for (int dt = 0; dt < 8; ++dt)
            Yf[dt] = __builtin_amdgcn_mfma_f32_16x16x32_bf16(vr1[dt], pb1, Yf[dt], 0, 0, 0);
        lacc = __builtin_amdgcn_mfma_f32_16x16x32_bf16(ones, pb1, lacc, 0, 0, 0);
        __builtin_amdgcn_s_setprio(0);

        __syncthreads();   // publishes next K tile
    }

    const int q = q0 + w * 16 + lr;
    const size_t ybase = ((size_t)(h * B_ + b) * N_ + q) * D_;
    #pragma unroll
    for (int dt = 0; dt < 8; ++dt) {
        short4_t s;
        #pragma unroll
        for (int r = 0; r < 4; ++r) s[r] = (short)f2bf(Yf[dt][r]);
        *reinterpret_cast<short4_t*>(&Yp[ybase + 16 * dt + lg * 4]) = s;
    }
    if (lg == 0)
        Lg[(size_t)(h * B_ + b) * N_ + q] = lacc[0];
}

// ---------------------------------------------------------------------------
// Kernel 2b: merge 4 split-K partials -> normalized bf16 Y [b][n][dd]
// ---------------------------------------------------------------------------
__global__ __launch_bounds__(256) void flash_merge(
    const unsigned short* __restrict__ Yp, const float* __restrict__ Lg,
    unsigned short* __restrict__ Yg)
{
    int idx = blockIdx.x * 256 + threadIdx.x;
    int dd2 = (idx & 63) * 2;
    int n   = (idx >> 6) & (N_ - 1);
    int b   = idx >> 18;
    float lsum = 0.f, a0 = 0.f, a1 = 0.f;
    #pragma unroll
    for (int h = 0; h < 4; ++h) {
        lsum += Lg[(size_t)(h * B_ + b) * N_ + n];
        unsigned int u = *reinterpret_cast<const unsigned int*>(
            &Yp[((size_t)(h * B_ + b) * N_ + n) * D_ + dd2]);
        a0 += bf2f(u);
        a1 += bf2f(u >> 16);
    }
    float inv = 1.f / lsum;
    unsigned int o = (unsigned int)f2bf(a0 * inv) | ((unsigned int)f2bf(a1 * inv) << 16);
    *reinterpret_cast<unsigned int*>(&Yg[((size_t)b * N_ + n) * D_ + dd2]) = o;
}

// ---------------------------------------------------------------------------
// Kernel 3: output projection + residual via MFMA, no LDS.
// grid (N/64, 2, B), 256 threads. out[b][c][n] = x + sum_dd w_out[c][dd]*Y[n][dd]
// D[n][c] = mfma(yf, wf): rows n = 16nt+4lg+r (contig 4), col c = lr.
// ---------------------------------------------------------------------------
__global__ __launch_bounds__(256) void out_mfma(
    const float* __restrict__ x, const unsigned short* __restrict__ woutF,
    const unsigned short* __restrict__ Y, float* __restrict__ out)
{
    const int n0 = blockIdx.x * 64;
    const int cy = blockIdx.y;      // c-half
    const int b  = blockIdx.z;

    const int t  = threadIdx.x;
    const int w  = t >> 6;
    const int l  = t & 63;
    const int lr = l & 15;
    const int lg = l >> 4;

    f32x4 acc[2][4];
    #pragma unroll
    for (int ci = 0; ci < 2; ++ci)
        #pragma unroll
        for (int nt = 0; nt < 4; ++nt) acc[ci][nt] = (f32x4){0.f, 0.f, 0.f, 0.f};

    const unsigned short* Yb = Y + (size_t)b * N_ * D_;
    #pragma unroll
    for (int kt = 0; kt < 4; ++kt) {
        short8_t yf[4];
        #pragma unroll
        for (int nt = 0; nt < 4; ++nt)
            yf[nt] = *reinterpret_cast<const short8_t*>(
                &Yb[(size_t)(n0 + 16 * nt + lr) * D_ + 32 * kt + 8 * lg]);
        #pragma unroll
        for (int ci = 0; ci < 2; ++ci) {
            const int c = cy * 128 + (2 * w + ci) * 16 + lr;
            short8_t wf = *reinterpret_cast<const short8_t*>(
                &woutF[(size_t)c * D_ + 32 * kt + 8 * lg]);
            #pragma unroll
            for (int nt = 0; nt < 4; ++nt)
                acc[ci][nt] = __builtin_amdgcn_mfma_f32_16x16x32_bf16(yf[nt], wf, acc[ci][nt], 0, 0, 0);
        }
    }

    #pragma unroll
    for (int ci = 0; ci < 2; ++ci) {
        const int c = cy * 128 + (2 * w + ci) * 16 + lr;
        #pragma unroll
        for (int nt = 0; nt < 4; ++nt) {
            size_t idx = ((size_t)b * C_ + c) * N_ + n0 + 16 * nt + 4 * lg;
            float4 xv = *reinterpret_cast<const float4*>(&x[idx]);
            *reinterpret_cast<float4*>(&out[idx]) =
                make_float4(acc[ci][nt][0] + xv.x, acc[ci][nt][1] + xv.y,
                            acc[ci][nt][2] + xv.z, acc[ci][nt][3] + xv.w);
        }
    }
}

// ---------------------------------------------------------------------------
extern "C" void kernel_launch(void* const* d_in, const int* in_sizes, int n_in,
                              void* d_out, int out_size, void* d_ws, size_t ws_size,
                              hipStream_t stream)
{
    const float* x       = (const float*)d_in[0];
    const float* w_theta = (const float*)d_in[1];
    const float* w_phi   = (const float*)d_in[2];
    const float* w_g     = (const float*)d_in[3];
    const float* w_out   = (const float*)d_in[4];
    float* outp = (float*)d_out;

    const size_t nq = (size_t)B_ * N_ * D_;              // 2,097,152 elements
    unsigned short* Qf    = (unsigned short*)d_ws;       // 4 MB fp16 (log2e-scaled)
    unsigned short* Kf    = Qf + nq;                     // 4 MB fp16
    unsigned short* Vt    = Kf + nq;                     // 4 MB bf16 (transposed)
    float*          Lg    = (float*)(Vt + nq);           // 256 KB
    unsigned short* wF    = (unsigned short*)(Lg + 4 * B_ * N_);  // 192 KB fp16
    unsigned short* woutF = wF + 3 * 128 * 256;          // 64 KB bf16
    unsigned short* Yp    = (unsigned short*)d_out;      // 16 MB scratch (bf16 x4)
    unsigned short* Y     = Kf;                          // merged Y aliases dead Kf

    wcvt_kernel<<<dim3(512), 256, 0, stream>>>(w_theta, w_phi, w_g, w_out, wF, woutF);
    proj_mfma<<<dim3(N_ / 32, B_), 256, 0, stream>>>(x, wF, Qf, Kf, Vt);
    flash_mfma<<<dim3(512), 512, 0, stream>>>(Qf, Kf, Vt, Yp, Lg);
    flash_merge<<<dim3((B_ * N_ * (D_ / 2)) / 256), 256, 0, stream>>>(Yp, Lg, Y);
    out_mfma<<<dim3(N_ / 64, 2, B_), 256, 0, stream>>>(x, woutF, Y, outp);
}

// Round 14
// 96.948 us; speedup vs baseline: 2.4473x; 2.4473x over previous
//
#include <hip/hip_runtime.h>

#define B_ 4
#define C_ 256
#define D_ 128
#define N_ 4096
#define LOG2E 1.44269504088896340736f
#define M_FIX 90.0f

typedef __attribute__((ext_vector_type(8))) short short8_t;
typedef __attribute__((ext_vector_type(4))) short short4_t;
typedef __attribute__((ext_vector_type(4))) float f32x4;
typedef _Float16 half8_t __attribute__((ext_vector_type(8)));
typedef _Float16 half4_t __attribute__((ext_vector_type(4)));

__device__ __forceinline__ unsigned short f2bf(float f) {
    union { float f; unsigned int u; } c; c.f = f;
    unsigned int r = (c.u + 0x7fffu + ((c.u >> 16) & 1u)) >> 16;
    return (unsigned short)r;
}
__device__ __forceinline__ float bf2f(unsigned int u) {
    union { unsigned int u; float f; } c; c.u = (u & 0xffffu) << 16;
    return c.f;
}
__device__ __forceinline__ unsigned short f2h(float f) {
    union { _Float16 h; unsigned short u; } c; c.h = (_Float16)f;
    return c.u;
}
__device__ __forceinline__ unsigned int cvtpk_bf16(float lo, float hi) {
    unsigned int r;
    asm("v_cvt_pk_bf16_f32 %0, %1, %2" : "=v"(r) : "v"(lo), "v"(hi));
    return r;
}

// direct HBM -> LDS DMA, 16 B per lane; lane i lands at lp + 16*i (linear)
#define GLOAD16(gp, lp)                                                     \
    __builtin_amdgcn_global_load_lds(                                       \
        (const __attribute__((address_space(1))) unsigned int*)(gp),        \
        (__attribute__((address_space(3))) unsigned int*)(lp), 16, 0, 0)

// ---------------------------------------------------------------------------
// Kernel 0: weight convert.
//   wF  [384][256] fp16 : rows 0-127 = LOG2E*w_theta, 128-255 = w_phi, 256-383 = w_g
//   woutF [256][128] bf16 : w_out
// ---------------------------------------------------------------------------
__global__ __launch_bounds__(256) void wcvt_kernel(
    const float* __restrict__ w_theta, const float* __restrict__ w_phi,
    const float* __restrict__ w_g, const float* __restrict__ w_out,
    unsigned short* __restrict__ wF, unsigned short* __restrict__ woutF)
{
    int tid = blockIdx.x * 256 + threadIdx.x;   // 131072 total
    if (tid < 3 * 32768) {
        int wi = tid >> 15, off = tid & 32767;
        const float* src = (wi == 0) ? w_theta : (wi == 1) ? w_phi : w_g;
        float v = src[off] * ((wi == 0) ? LOG2E : 1.f);
        wF[tid] = f2h(v);
    } else {
        int off = tid - 3 * 32768;
        woutF[off] = f2bf(w_out[off]);
    }
}

// ---------------------------------------------------------------------------
// Kernel 1: projections via MFMA.
// grid (N/32, B), 256 threads (4 waves). Block: n-tile 32, all 384 dd, k=256.
// x tile staged in LDS fp16 [256 c][32 n] (stride 36). x-fragments reused as
// A (for V, D[n][dd]) and B (for Q/K, D[dd][n]) operands. w frags from L2.
//   Q[b][n][dd] fp16 (log2e pre-scaled), K[b][n][dd] fp16, Vt[b][dd][n] bf16
// ---------------------------------------------------------------------------
__global__ __launch_bounds__(256) void proj_mfma(
    const float* __restrict__ x, const unsigned short* __restrict__ wF,
    unsigned short* __restrict__ Qf, unsigned short* __restrict__ Kf,
    unsigned short* __restrict__ Vt)
{
    const int n0 = blockIdx.x * 32;
    const int b  = blockIdx.y;

    __shared__ _Float16 xs[256 * 36];   // [c][n], stride 36 (2-way-free reads)

    const int t  = threadIdx.x;
    const int w  = t >> 6;
    const int l  = t & 63;
    const int lr = l & 15;
    const int lg = l >> 4;

    // stage x tile: pass p, thread: c = 32p + (t>>3), n = 4*(t&7)
    const float* xb = x + (size_t)b * C_ * N_;
    {
        const int cb = t >> 3, n2 = t & 7;
        #pragma unroll
        for (int p = 0; p < 8; ++p) {
            const int c = 32 * p + cb;
            float4 v = *reinterpret_cast<const float4*>(&xb[(size_t)c * N_ + n0 + 4 * n2]);
            union { _Float16 h[4]; uint2 u; } pk;
            pk.h[0] = (_Float16)v.x; pk.h[1] = (_Float16)v.y;
            pk.h[2] = (_Float16)v.z; pk.h[3] = (_Float16)v.w;
            *reinterpret_cast<uint2*>(&xs[c * 36 + 4 * n2]) = pk.u;
        }
    }
    __syncthreads();

    // wave w owns dd-tiles gt = 6w .. 6w+5 (each 16 dd rows of the 384)
    f32x4 acc[6][2];
    #pragma unroll
    for (int d = 0; d < 6; ++d)
        #pragma unroll
        for (int nt = 0; nt < 2; ++nt) acc[d][nt] = (f32x4){0.f, 0.f, 0.f, 0.f};

    #pragma unroll
    for (int kt = 0; kt < 8; ++kt) {
        // x fragments: lane (lr,lg) holds x[c = 32kt+8lg+j][n = 16nt+lr]
        half8_t xf[2];
        #pragma unroll
        for (int nt = 0; nt < 2; ++nt)
            #pragma unroll
            for (int j = 0; j < 8; ++j)
                xf[nt][j] = xs[(32 * kt + 8 * lg + j) * 36 + 16 * nt + lr];
        #pragma unroll
        for (int d = 0; d < 6; ++d) {
            const int gt = 6 * w + d;
            half8_t wf = *reinterpret_cast<const half8_t*>(
                &wF[(size_t)(16 * gt + lr) * 256 + 32 * kt + 8 * lg]);
            if (gt < 16) {   // Q/K: D[dd][n]
                #pragma unroll
                for (int nt = 0; nt < 2; ++nt)
                    acc[d][nt] = __builtin_amdgcn_mfma_f32_16x16x32_f16(wf, xf[nt], acc[d][nt], 0, 0, 0);
            } else {         // V: D[n][dd]
                #pragma unroll
                for (int nt = 0; nt < 2; ++nt)
                    acc[d][nt] = __builtin_amdgcn_mfma_f32_16x16x32_f16(xf[nt], wf, acc[d][nt], 0, 0, 0);
            }
        }
    }

    // stores
    #pragma unroll
    for (int d = 0; d < 6; ++d) {
        const int gt = 6 * w + d;
        #pragma unroll
        for (int nt = 0; nt < 2; ++nt) {
            if (gt < 16) {
                // D[dd][n]: col n = 16nt+lr, rows dd = (gt&7)*16 + 4lg + r
                unsigned short* o = (gt < 8) ? Qf : Kf;
                half4_t s;
                #pragma unroll
                for (int r = 0; r < 4; ++r) s[r] = (_Float16)acc[d][nt][r];
                size_t idx = ((size_t)(b * N_ + n0 + 16 * nt + lr)) * D_ + (gt & 7) * 16 + 4 * lg;
                *reinterpret_cast<half4_t*>(&o[idx]) = s;
            } else {
                // D[n][dd]: col dd = (gt-16)*16 + lr, rows n = 16nt + 4lg + r
                short4_t s;
                #pragma unroll
                for (int r = 0; r < 4; ++r) s[r] = (short)f2bf(acc[d][nt][r]);
                size_t idx = ((size_t)b * D_ + (gt - 16) * 16 + lr) * N_ + n0 + 16 * nt + 4 * lg;
                *reinterpret_cast<short4_t*>(&Vt[idx]) = s;
            }
        }
    }
}

// ---------------------------------------------------------------------------
// Kernel 2: MFMA flash attention (r12 structure: K+V in LDS, gload_lds dbuf).
// vs r12, two bit-exact address micro-opts:
//  - hoisted + pinned swizzled LDS offsets (koffe/voffe)
//  - hoisted + pinned ds_bpermute addresses (a0/a1) replacing __shfl
// ---------------------------------------------------------------------------
__global__ __launch_bounds__(512, 4) void flash_mfma(
    const unsigned short* __restrict__ Qg,   // fp16 [b][n][dd], log2e-scaled
    const unsigned short* __restrict__ Kg,   // fp16 [b][n][dd]
    const unsigned short* __restrict__ Vg,   // bf16 [b][dd][n]
    unsigned short* __restrict__ Yp, float* __restrict__ Lg)
{
    const int id    = blockIdx.x;
    const int local = id >> 3;
    const int group = (id & 7) * 2 + (local >> 5);
    const int qblk  = local & 31;
    const int h     = group & 3;
    const int b     = group >> 2;
    const int q0    = qblk * 128;
    const int m_base = h * 1024;

    __shared__ unsigned short Ks[2][64 * 128];   // fp16, swizzled c16 = j^(row&15)
    __shared__ unsigned short Vs[2][128 * 64];   // bf16, swizzled c8  = j^(row&7)

    const int t  = threadIdx.x;
    const int w  = t >> 6;
    const int l  = t & 63;
    const int lr = l & 15;
    const int lg = l >> 4;

    half8_t qf[4];
    {
        const unsigned short* qp =
            Qg + ((size_t)(b * N_ + q0 + w * 16 + lr)) * D_ + lg * 8;
        #pragma unroll
        for (int kt = 0; kt < 4; ++kt)
            qf[kt] = *reinterpret_cast<const half8_t*>(qp + 32 * kt);
    }

    f32x4 Yf[8];
    #pragma unroll
    for (int i = 0; i < 8; ++i) Yf[i] = (f32x4){0.f, 0.f, 0.f, 0.f};
    f32x4 lacc = (f32x4){0.f, 0.f, 0.f, 0.f};   // l[q=lr] via ones-row MFMA

    short8_t ones;
    #pragma unroll
    for (int i = 0; i < 8; ++i) ones[i] = (short)0x3F80;   // bf16 1.0

    // hoisted loop-invariant addressing, pinned against rematerialization
    int koffe[4], voffe[2];
    #pragma unroll
    for (int kt = 0; kt < 4; ++kt)
        koffe[kt] = lr * 128 + (((lg + 4 * kt) ^ lr) * 8);
    #pragma unroll
    for (int mk = 0; mk < 2; ++mk)
        voffe[mk] = lr * 64 + (((lg + 4 * mk) ^ (lr & 7)) * 8);
    int a0 = 4 * (lr + 32 * (lg & 1));   // bpermute byte addr, wd 0..1
    int a1 = a0 + 64;                    // wd 2..3 (+16 lanes)
    asm volatile("" : "+v"(koffe[0]), "+v"(koffe[1]), "+v"(koffe[2]),
                      "+v"(koffe[3]), "+v"(voffe[0]), "+v"(voffe[1]),
                      "+v"(a0), "+v"(a1));

    const unsigned short* Kbp = Kg + (size_t)b * N_ * D_;
    const unsigned short* Vbp = Vg + (size_t)b * D_ * N_;
    const int krow0 = 8 * w + (l >> 4);
    const int krow1 = krow0 + 4;
    const unsigned short* kp0 = Kbp + (size_t)(m_base + krow0) * D_ + (((l & 15) ^ (krow0 & 15)) * 8);
    const unsigned short* kp1 = Kbp + (size_t)(m_base + krow1) * D_ + (((l & 15) ^ (krow1 & 15)) * 8);
    const int vrow0 = 16 * w + (l >> 3);
    const int vrow1 = vrow0 + 8;
    const unsigned short* vp0 = Vbp + (size_t)vrow0 * N_ + m_base + (((l & 7) ^ (vrow0 & 7)) * 8);
    const unsigned short* vp1 = Vbp + (size_t)vrow1 * N_ + m_base + (((l & 7) ^ (vrow1 & 7)) * 8);

    GLOAD16(kp0, &Ks[0][(8 * w) * 128]);
    GLOAD16(kp1, &Ks[0][(8 * w + 4) * 128]);
    GLOAD16(vp0, &Vs[0][(16 * w) * 64]);
    GLOAD16(vp1, &Vs[0][(16 * w + 8) * 64]);
    __syncthreads();

    for (int it = 0; it < 16; ++it) {
        const int cur = it & 1;
        if (it + 1 < 16) {
            const size_t ko = (size_t)(it + 1) * 8192;
            const size_t vo = (size_t)(it + 1) * 64;
            GLOAD16(kp0 + ko, &Ks[cur ^ 1][(8 * w) * 128]);
            GLOAD16(kp1 + ko, &Ks[cur ^ 1][(8 * w + 4) * 128]);
            GLOAD16(vp0 + vo, &Vs[cur ^ 1][(16 * w) * 64]);
            GLOAD16(vp1 + vo, &Vs[cur ^ 1][(16 * w + 8) * 64]);
        }

        // S starts at -M_FIX (fixed-max shift folded into the accumulator)
        f32x4 S[4];
        #pragma unroll
        for (int mt = 0; mt < 4; ++mt)
            S[mt] = (f32x4){-M_FIX, -M_FIX, -M_FIX, -M_FIX};
        __builtin_amdgcn_s_setprio(1);
        #pragma unroll
        for (int kt = 0; kt < 4; ++kt) {
            #pragma unroll
            for (int mt = 0; mt < 4; ++mt) {
                half8_t kf = *reinterpret_cast<const half8_t*>(
                    &Ks[cur][koffe[kt] + 2048 * mt]);
                S[mt] = __builtin_amdgcn_mfma_f32_16x16x32_f16(kf, qf[kt], S[mt], 0, 0, 0);
            }
        }
        __builtin_amdgcn_s_setprio(0);

        #pragma unroll
        for (int mt = 0; mt < 4; ++mt)
            #pragma unroll
            for (int r = 0; r < 4; ++r)
                S[mt][r] = exp2f(S[mt][r]);
        unsigned int pk[4][2];
        #pragma unroll
        for (int mt = 0; mt < 4; ++mt) {
            pk[mt][0] = cvtpk_bf16(S[mt][0], S[mt][1]);
            pk[mt][1] = cvtpk_bf16(S[mt][2], S[mt][3]);
        }

        __builtin_amdgcn_s_setprio(1);
        #pragma unroll
        for (int mk = 0; mk < 2; ++mk) {
            short8_t pb;
            unsigned int* pbw = reinterpret_cast<unsigned int*>(&pb);
            #pragma unroll
            for (int wd = 0; wd < 4; ++wd) {
                const int ad = (wd >> 1) ? a1 : a0;
                int vA = __builtin_amdgcn_ds_bpermute(ad, (int)pk[2 * mk][wd & 1]);
                int vB = __builtin_amdgcn_ds_bpermute(ad, (int)pk[2 * mk + 1][wd & 1]);
                pbw[wd] = (unsigned int)((lg >> 1) ? vB : vA);
            }
            #pragma unroll
            for (int dt = 0; dt < 8; ++dt) {
                short8_t vf = *reinterpret_cast<const short8_t*>(
                    &Vs[cur][voffe[mk] + 1024 * dt]);
                Yf[dt] = __builtin_amdgcn_mfma_f32_16x16x32_bf16(vf, pb, Yf[dt], 0, 0, 0);
            }
            // l-row: sum_m P[m][q] accumulated by the matrix pipe
            lacc = __builtin_amdgcn_mfma_f32_16x16x32_bf16(ones, pb, lacc, 0, 0, 0);
        }
        __builtin_amdgcn_s_setprio(0);

        __syncthreads();
    }

    const int q = q0 + w * 16 + lr;
    const size_t ybase = ((size_t)(h * B_ + b) * N_ + q) * D_;
    #pragma unroll
    for (int dt = 0; dt < 8; ++dt) {
        short4_t s;
        #pragma unroll
        for (int r = 0; r < 4; ++r) s[r] = (short)f2bf(Yf[dt][r]);
        *reinterpret_cast<short4_t*>(&Yp[ybase + 16 * dt + lg * 4]) = s;
    }
    if (lg == 0)
        Lg[(size_t)(h * B_ + b) * N_ + q] = lacc[0];
}

// ---------------------------------------------------------------------------
// Kernel 2b: merge 4 split-K partials -> normalized bf16 Y [b][n][dd]
// ---------------------------------------------------------------------------
__global__ __launch_bounds__(256) void flash_merge(
    const unsigned short* __restrict__ Yp, const float* __restrict__ Lg,
    unsigned short* __restrict__ Yg)
{
    int idx = blockIdx.x * 256 + threadIdx.x;
    int dd2 = (idx & 63) * 2;
    int n   = (idx >> 6) & (N_ - 1);
    int b   = idx >> 18;
    float lsum = 0.f, a0 = 0.f, a1 = 0.f;
    #pragma unroll
    for (int h = 0; h < 4; ++h) {
        lsum += Lg[(size_t)(h * B_ + b) * N_ + n];
        unsigned int u = *reinterpret_cast<const unsigned int*>(
            &Yp[((size_t)(h * B_ + b) * N_ + n) * D_ + dd2]);
        a0 += bf2f(u);
        a1 += bf2f(u >> 16);
    }
    float inv = 1.f / lsum;
    unsigned int o = (unsigned int)f2bf(a0 * inv) | ((unsigned int)f2bf(a1 * inv) << 16);
    *reinterpret_cast<unsigned int*>(&Yg[((size_t)b * N_ + n) * D_ + dd2]) = o;
}

// ---------------------------------------------------------------------------
// Kernel 3: output projection + residual via MFMA, no LDS.
// grid (N/64, 2, B), 256 threads. out[b][c][n] = x + sum_dd w_out[c][dd]*Y[n][dd]
// D[n][c] = mfma(yf, wf): rows n = 16nt+4lg+r (contig 4), col c = lr.
// ---------------------------------------------------------------------------
__global__ __launch_bounds__(256) void out_mfma(
    const float* __restrict__ x, const unsigned short* __restrict__ woutF,
    const unsigned short* __restrict__ Y, float* __restrict__ out)
{
    const int n0 = blockIdx.x * 64;
    const int cy = blockIdx.y;      // c-half
    const int b  = blockIdx.z;

    const int t  = threadIdx.x;
    const int w  = t >> 6;
    const int l  = t & 63;
    const int lr = l & 15;
    const int lg = l >> 4;

    f32x4 acc[2][4];
    #pragma unroll
    for (int ci = 0; ci < 2; ++ci)
        #pragma unroll
        for (int nt = 0; nt < 4; ++nt) acc[ci][nt] = (f32x4){0.f, 0.f, 0.f, 0.f};

    const unsigned short* Yb = Y + (size_t)b * N_ * D_;
    #pragma unroll
    for (int kt = 0; kt < 4; ++kt) {
        short8_t yf[4];
        #pragma unroll
        for (int nt = 0; nt < 4; ++nt)
            yf[nt] = *reinterpret_cast<const short8_t*>(
                &Yb[(size_t)(n0 + 16 * nt + lr) * D_ + 32 * kt + 8 * lg]);
        #pragma unroll
        for (int ci = 0; ci < 2; ++ci) {
            const int c = cy * 128 + (2 * w + ci) * 16 + lr;
            short8_t wf = *reinterpret_cast<const short8_t*>(
                &woutF[(size_t)c * D_ + 32 * kt + 8 * lg]);
            #pragma unroll
            for (int nt = 0; nt < 4; ++nt)
                acc[ci][nt] = __builtin_amdgcn_mfma_f32_16x16x32_bf16(yf[nt], wf, acc[ci][nt], 0, 0, 0);
        }
    }

    #pragma unroll
    for (int ci = 0; ci < 2; ++ci) {
        const int c = cy * 128 + (2 * w + ci) * 16 + lr;
        #pragma unroll
        for (int nt = 0; nt < 4; ++nt) {
            size_t idx = ((size_t)b * C_ + c) * N_ + n0 + 16 * nt + 4 * lg;
            float4 xv = *reinterpret_cast<const float4*>(&x[idx]);
            *reinterpret_cast<float4*>(&out[idx]) =
                make_float4(acc[ci][nt][0] + xv.x, acc[ci][nt][1] + xv.y,
                            acc[ci][nt][2] + xv.z, acc[ci][nt][3] + xv.w);
        }
    }
}

// ---------------------------------------------------------------------------
extern "C" void kernel_launch(void* const* d_in, const int* in_sizes, int n_in,
                              void* d_out, int out_size, void* d_ws, size_t ws_size,
                              hipStream_t stream)
{
    const float* x       = (const float*)d_in[0];
    const float* w_theta = (const float*)d_in[1];
    const float* w_phi   = (const float*)d_in[2];
    const float* w_g     = (const float*)d_in[3];
    const float* w_out   = (const float*)d_in[4];
    float* outp = (float*)d_out;

    const size_t nq = (size_t)B_ * N_ * D_;              // 2,097,152 elements
    unsigned short* Qf    = (unsigned short*)d_ws;       // 4 MB fp16 (log2e-scaled)
    unsigned short* Kf    = Qf + nq;                     // 4 MB fp16
    unsigned short* Vt    = Kf + nq;                     // 4 MB bf16 (transposed)
    float*          Lg    = (float*)(Vt + nq);           // 256 KB
    unsigned short* wF    = (unsigned short*)(Lg + 4 * B_ * N_);  // 192 KB fp16
    unsigned short* woutF = wF + 3 * 128 * 256;          // 64 KB bf16
    unsigned short* Yp    = (unsigned short*)d_out;      // 16 MB scratch (bf16 x4)
    unsigned short* Y     = Kf;                          // merged Y aliases dead Kf

    wcvt_kernel<<<dim3(512), 256, 0, stream>>>(w_theta, w_phi, w_g, w_out, wF, woutF);
    proj_mfma<<<dim3(N_ / 32, B_), 256, 0, stream>>>(x, wF, Qf, Kf, Vt);
    flash_mfma<<<dim3(512), 512, 0, stream>>>(Qf, Kf, Vt, Yp, Lg);
    flash_merge<<<dim3((B_ * N_ * (D_ / 2)) / 256), 256, 0, stream>>>(Yp, Lg, Y);
    out_mfma<<<dim3(N_ / 64, 2, B_), 256, 0, stream>>>(x, woutF, Y, outp);
}